// Round 15
// baseline (63.839 us; speedup 1.0000x reference)
//
#include <hip/hip_runtime.h>
#include <math.h>

#define T_STEPS 256
#define BATCH   128
#define DIMD    512
#define NROWS   (T_STEPS * BATCH)   // 32768
#define PF      16                  // chunk size (LDS staging granularity)
#define NCHUNK  (T_STEPS / PF)      // 16
#define WRITER_BLOCKS 258
#define GEMV_BLOCKS 2048            // 16 rows/block, 4 rows/wave

#define INV2PI  0.15915494309189535f
#define TWO_L2E 2.8853900817779268f

#define AGENT __HIP_MEMORY_SCOPE_AGENT

typedef float f32x4 __attribute__((ext_vector_type(4)));

#if __has_builtin(__builtin_amdgcn_sinf)
#define HW_SIN(x) __builtin_amdgcn_sinf(x)   // sin(2*pi*x), x in revolutions
#else
__device__ __forceinline__ float HW_SIN(float x) { return __sinf(x * 6.283185307179586f); }
#endif
#if __has_builtin(__builtin_amdgcn_exp2f)
#define EXP2(x) __builtin_amdgcn_exp2f(x)
#else
#define EXP2(x) exp2f(x)
#endif
#if __has_builtin(__builtin_amdgcn_rcpf)
#define RCP(x) __builtin_amdgcn_rcpf(x)
#else
#define RCP(x) (1.0f / (x))
#endif

// Horner deg-7
#define P7(s, c7,c6,c5,c4,c3,c2,c1,c0) \
  fmaf(fmaf(fmaf(fmaf(fmaf(fmaf(fmaf((c7),(s),(c6)),(s),(c5)),(s),(c4)),(s),(c3)),(s),(c2)),(s),(c1)),(s),(c0))

// Agent-scope relaxed ops (sc-flagged; no wbl2/inv cache maintenance).
__device__ __forceinline__ void  st_rlx(float* p, float v) {
    __hip_atomic_store(p, v, __ATOMIC_RELAXED, AGENT);
}
__device__ __forceinline__ void  st_rlx_i(int* p, int v) {
    __hip_atomic_store(p, v, __ATOMIC_RELAXED, AGENT);
}
__device__ __forceinline__ int   ld_rlx_i(const int* p) {
    return __hip_atomic_load(p, __ATOMIC_RELAXED, AGENT);
}
#define CFENCE()  asm volatile("" ::: "memory")

// ---------------------------------------------------------------------------
// prep: block 0 = qconsts (4 gates, one wave each); blocks 1.. = gemv.
// qconsts now also FITS, per gate, the deg-7 Chebyshev interpolant of
//   G(s) = act(A + R*s),  s in [-1,1]   (act = sigmoid for f,i,o; tanh for g)
// — valid because |A + R*s| <= |E| <= 1 (Z-expectation of a unit state).
// gc layout (floats): [8g..8g+7] monomial coeffs of gate g;
//                     [32+g] = sumWh/2pi; [36+g] = phi_rev.
// X4[t*B+b] = (dot + b0)/2pi  (phase folded by the staging waves).
// ---------------------------------------------------------------------------
__global__ __launch_bounds__(256) void prep(
    const float* __restrict__ inp,
    const float* __restrict__ Wf, const float* __restrict__ Wi,
    const float* __restrict__ Wg, const float* __restrict__ Wo,
    const float* __restrict__ bfp, const float* __restrict__ bip,
    const float* __restrict__ bgp, const float* __restrict__ bop,
    const float* __restrict__ Pf, const float* __restrict__ Pi,
    const float* __restrict__ Pg, const float* __restrict__ Po,
    float* __restrict__ gc, int* __restrict__ hProg,
    float4* __restrict__ X4)
{
    const int bid  = blockIdx.x;
    const int wv   = threadIdx.x >> 6;
    const int lane = threadIdx.x & 63;

    if (bid == 0) {
        // ================= qconsts =================
        if (threadIdx.x == 0) { hProg[0] = 0; hProg[1] = 0; }
        const int g = wv;
        const float* P = (g == 0) ? Pf : (g == 1) ? Pi : (g == 2) ? Pg : Po;
        const float* W = (g == 0) ? Wf : (g == 1) ? Wi : (g == 2) ? Wg : Wo;

        __shared__ float s0r[4][256], s0i[4][256], s1r[4][256], s1i[4][256];

#pragma unroll
        for (int j = 0; j < 4; ++j) {
            const int k = lane + 64 * j;
            s0r[g][k] = (k == 0)   ? 1.0f : 0.0f;  s0i[g][k] = 0.0f;
            s1r[g][k] = (k == 128) ? 1.0f : 0.0f;  s1i[g][k] = 0.0f;
        }
        __syncthreads();

        for (int l = 0; l < 2; ++l) {
            for (int w = 0; w < 8; ++w) {
                const float phi = P[l * 24 + w * 3 + 0];
                const float th  = P[l * 24 + w * 3 + 1];
                const float om  = P[l * 24 + w * 3 + 2];
                float sh, chh; __sincosf(0.5f * th, &sh, &chh);
                float sp, cp;  __sincosf(0.5f * (phi + om), &sp, &cp);
                float sm, cm;  __sincosf(0.5f * (phi - om), &sm, &cm);
                const float m00r =  cp * chh, m00i = -sp * chh;
                const float m01r = -cm * sh,  m01i = -sm * sh;
                const float m10r =  cm * sh,  m10i = -sm * sh;
                const float m11r =  cp * chh, m11i =  sp * chh;

                const int shift = 7 - w;
                const int mask  = 1 << shift;

                float n0r[4], n0i[4], n1r[4], n1i[4];
#pragma unroll
                for (int j = 0; j < 4; ++j) {
                    const int k  = lane + 64 * j;
                    const int bit = (k >> shift) & 1;
                    const int i0 = k & ~mask, i1 = k | mask;
                    const float a0r = s0r[g][i0], a0i = s0i[g][i0];
                    const float a1r = s0r[g][i1], a1i = s0i[g][i1];
                    const float b0r = s1r[g][i0], b0i = s1i[g][i0];
                    const float b1r = s1r[g][i1], b1i = s1i[g][i1];
                    const float mr0 = bit ? m10r : m00r, mi0 = bit ? m10i : m00i;
                    const float mr1 = bit ? m11r : m01r, mi1 = bit ? m11i : m01i;
                    n0r[j] = mr0 * a0r - mi0 * a0i + mr1 * a1r - mi1 * a1i;
                    n0i[j] = mr0 * a0i + mi0 * a0r + mr1 * a1i + mi1 * a1r;
                    n1r[j] = mr0 * b0r - mi0 * b0i + mr1 * b1r - mi1 * b1i;
                    n1i[j] = mr0 * b0i + mi0 * b0r + mr1 * b1i + mi1 * b1r;
                }
                __syncthreads();
#pragma unroll
                for (int j = 0; j < 4; ++j) {
                    const int k = lane + 64 * j;
                    s0r[g][k] = n0r[j]; s0i[g][k] = n0i[j];
                    s1r[g][k] = n1r[j]; s1i[g][k] = n1i[j];
                }
                __syncthreads();
            }
            // CNOT chain permutation
            float n0r[4], n0i[4], n1r[4], n1i[4];
#pragma unroll
            for (int j = 0; j < 4; ++j) {
                int src = lane + 64 * j;
                for (int w = 6; w >= 0; --w) {
                    const int cb = (src >> (7 - w)) & 1;
                    src ^= cb << (6 - w);
                }
                n0r[j] = s0r[g][src]; n0i[j] = s0i[g][src];
                n1r[j] = s1r[g][src]; n1i[j] = s1i[g][src];
            }
            __syncthreads();
#pragma unroll
            for (int j = 0; j < 4; ++j) {
                const int k = lane + 64 * j;
                s0r[g][k] = n0r[j]; s0i[g][k] = n0i[j];
                s1r[g][k] = n1r[j]; s1i[g][k] = n1i[j];
            }
            __syncthreads();
        }

        float t00 = 0, t11 = 0, t01 = 0;
#pragma unroll
        for (int j = 0; j < 4; ++j) {
            const int k = lane + 64 * j;
            const float z = (k < 128) ? 1.0f : -1.0f;
            t00 += z * (s0r[g][k] * s0r[g][k] + s0i[g][k] * s0i[g][k]);
            t11 += z * (s1r[g][k] * s1r[g][k] + s1i[g][k] * s1i[g][k]);
            t01 += z * (s0i[g][k] * s1r[g][k] - s0r[g][k] * s1i[g][k]);
        }
        float tsw = 0;
#pragma unroll
        for (int j = 0; j < 8; ++j) tsw += W[512 + lane + 64 * j];

        for (int off = 32; off; off >>= 1) {
            t00 += __shfl_xor(t00, off);
            t11 += __shfl_xor(t11, off);
            t01 += __shfl_xor(t01, off);
            tsw += __shfl_xor(tsw, off);
        }
        if (lane == 0) {
            const float A  = 0.5f * (t00 + t11);
            const float Bc = 0.5f * (t00 - t11);
            const float Bs = -t01;
            const float R  = sqrtf(Bc * Bc + Bs * Bs);
            const float ph = atan2f(Bc, Bs) * INV2PI;

            // ---- deg-7 Chebyshev interpolation of act(A + R*s) ----
            double xn[8], a[8];
            for (int j = 0; j < 8; ++j) {
                xn[j] = cos(M_PI * (2 * j + 1) / 16.0);
                const double e = (double)A + (double)R * xn[j];
                a[j] = (g == 2) ? tanh(e) : 1.0 / (1.0 + exp(-e));
            }
            for (int k = 1; k < 8; ++k)
                for (int j = 7; j >= k; --j)
                    a[j] = (a[j] - a[j - 1]) / (xn[j] - xn[j - k]);
            double m[8] = {0, 0, 0, 0, 0, 0, 0, 0};
            m[0] = a[7];
            for (int k = 6; k >= 0; --k) {
                for (int i = 7; i >= 1; --i) m[i] = m[i - 1] - xn[k] * m[i];
                m[0] = -xn[k] * m[0] + a[k];
            }
            for (int j = 0; j < 8; ++j) gc[8 * g + j] = (float)m[j];
            gc[32 + g] = tsw * INV2PI;
            gc[36 + g] = ph;
        }
        return;
    }

    // ================= gemv: 4 rows per wave =================
    const int rowbase = (bid - 1) * 16 + wv * 4;

    const float4* wfp = (const float4*)Wf;
    const float4* wip = (const float4*)Wi;
    const float4* wgp = (const float4*)Wg;
    const float4* wop = (const float4*)Wo;
    const float4 fa = wfp[lane], fb = wfp[lane + 64];
    const float4 ia = wip[lane], ib = wip[lane + 64];
    const float4 ga = wgp[lane], gb = wgp[lane + 64];
    const float4 oa = wop[lane], ob = wop[lane + 64];

    const float4* xr = (const float4*)(inp + (size_t)rowbase * DIMD);
    float sums[4][4];   // [row][gate]
#pragma unroll
    for (int r = 0; r < 4; ++r) {
        const float4 xa = xr[r * 128 + lane];
        const float4 xb = xr[r * 128 + lane + 64];
        sums[r][0] = xa.x * fa.x + xa.y * fa.y + xa.z * fa.z + xa.w * fa.w
                   + xb.x * fb.x + xb.y * fb.y + xb.z * fb.z + xb.w * fb.w;
        sums[r][1] = xa.x * ia.x + xa.y * ia.y + xa.z * ia.z + xa.w * ia.w
                   + xb.x * ib.x + xb.y * ib.y + xb.z * ib.z + xb.w * ib.w;
        sums[r][2] = xa.x * ga.x + xa.y * ga.y + xa.z * ga.z + xa.w * ga.w
                   + xb.x * gb.x + xb.y * gb.y + xb.z * gb.z + xb.w * gb.w;
        sums[r][3] = xa.x * oa.x + xa.y * oa.y + xa.z * oa.z + xa.w * oa.w
                   + xb.x * ob.x + xb.y * ob.y + xb.z * ob.z + xb.w * ob.w;
    }
#pragma unroll
    for (int r = 0; r < 4; ++r)
#pragma unroll
        for (int g = 0; g < 4; ++g)
            for (int off = 32; off; off >>= 1)
                sums[r][g] += __shfl_xor(sums[r][g], off);

    if (lane == 0) {
        const float b0f = bfp[0], b0i = bip[0], b0g = bgp[0], b0o = bop[0];
#pragma unroll
        for (int r = 0; r < 4; ++r) {
            X4[rowbase + r] = make_float4((sums[r][0] + b0f) * INV2PI,
                                          (sums[r][1] + b0i) * INV2PI,
                                          (sums[r][2] + b0g) * INV2PI,
                                          (sums[r][3] + b0o) * INV2PI);
        }
    }
}

// ---------------------------------------------------------------------------
// Fused scan + broadcast. Grid 259 x 256.
// Block 0: producer/consumer split (R14 structure). Consumers now use the
// fitted polynomials: per step 4 sin + 28 fma + exp2/rcp tanh tail —
// 6 transcendentals instead of 11, chain depth 3 trans instead of 5.
// Blocks 1..258: writers (deficit-proportional sleep, NT output stores).
// ---------------------------------------------------------------------------
__global__ __launch_bounds__(256) void scan_write(
    const float4* __restrict__ X4, const float* __restrict__ gc,
    float* __restrict__ Hs, float* __restrict__ cfin,
    float4* __restrict__ out4, int* __restrict__ hProg)
{
    const int bid  = blockIdx.x;
    const int tid  = threadIdx.x;
    const int wv   = tid >> 6;
    const int lane = tid & 63;

    if (bid == 0) {
        __shared__ float4 xbuf[2][PF][BATCH];   // 64 KB double buffer

        const float phf = gc[36], phi_ = gc[37], phg = gc[38], pho = gc[39];

        if (tid >= BATCH) {
            // -------- producer prologue: stage chunk 0 into buf 0 --------
            const int b = tid - BATCH;
#pragma unroll
            for (int j = 0; j < PF; ++j) {
                const float4 v = X4[j * BATCH + b];
                xbuf[0][j][b] = make_float4(v.x + phf, v.y + phi_,
                                            v.z + phg, v.w + pho);
            }
        }
        __syncthreads();

        // gate polynomial coefficients (named scalars — rule #20)
        const float f0 = gc[0],  f1 = gc[1],  f2 = gc[2],  f3 = gc[3];
        const float f4 = gc[4],  f5 = gc[5],  f6 = gc[6],  f7 = gc[7];
        const float i0 = gc[8],  i1 = gc[9],  i2 = gc[10], i3 = gc[11];
        const float i4 = gc[12], i5 = gc[13], i6 = gc[14], i7 = gc[15];
        const float g0 = gc[16], g1 = gc[17], g2 = gc[18], g3 = gc[19];
        const float g4 = gc[20], g5 = gc[21], g6 = gc[22], g7 = gc[23];
        const float o0 = gc[24], o1 = gc[25], o2 = gc[26], o3 = gc[27];
        const float o4 = gc[28], o5 = gc[29], o6 = gc[30], o7 = gc[31];
        const float swf = gc[32], swi = gc[33], swg = gc[34], swo = gc[35];

        float c = 0.0f, h = 0.0f;
        for (int k = 0; k < NCHUNK; ++k) {
            const int tb = k * PF;
            if (tid >= BATCH) {
                // -------- producer: stage chunk k+1 (pad covers k=15) ----
                const int b  = tid - BATCH;
                const int nb = (k + 1) & 1;
#pragma unroll
                for (int j = 0; j < PF; ++j) {
                    const float4 v = X4[(tb + PF + j) * BATCH + b];
                    xbuf[nb][j][b] = make_float4(v.x + phf, v.y + phi_,
                                                 v.z + phg, v.w + pho);
                }
            } else {
                // -------- consumer: 16 steps from xbuf[k&1] --------------
                const int b  = tid;
                const int cb = k & 1;
                float4 xv = xbuf[cb][0][b];
#pragma unroll
                for (int j = 0; j < PF; ++j) {
                    float4 nx;
                    if (j < PF - 1) nx = xbuf[cb][j + 1][b];  // 2-deep pipe
                    const float thf = fmaf(h, swf, xv.x);
                    const float thi = fmaf(h, swi, xv.y);
                    const float thg = fmaf(h, swg, xv.z);
                    const float tho = fmaf(h, swo, xv.w);
                    const float sf = HW_SIN(thf);
                    const float si = HW_SIN(thi);
                    const float sg = HW_SIN(thg);
                    const float so = HW_SIN(tho);
                    const float fg = P7(sf, f7,f6,f5,f4,f3,f2,f1,f0);
                    const float ig = P7(si, i7,i6,i5,i4,i3,i2,i1,i0);
                    const float gg = P7(sg, g7,g6,g5,g4,g3,g2,g1,g0);
                    const float og = P7(so, o7,o6,o5,o4,o3,o2,o1,o0);
                    c = fmaf(fg, c, ig * gg);
                    const float ec = EXP2(c * TWO_L2E);
                    const float y  = RCP(ec + 1.0f);
                    const float t2 = og * y;
                    h = fmaf(-2.0f, t2, og);                  // o*tanh(c)
                    st_rlx(&Hs[(tb + j) * BATCH + b], h);
                    xv = nx;
                }
                if (k == NCHUNK - 1) st_rlx(&cfin[b], c);
            }
            __syncthreads();   // handoff; each wave drains its own vm ops
            if ((k & 3) == 3 && tid == 0)
                st_rlx_i(&hProg[0], tb + PF);   // t = 64,128,192,256
        }
        return;
    }

    // ---------------- writers ----------------
    const int t  = bid - 1;           // 0..257 (256=hx, 257=cx)
    const int qd = wv;                // quarter: b in [qd*32, qd*32+32)
    const int need = (t < 256) ? ((t >> 6) + 1) << 6 : 256;

    int cur = ld_rlx_i(&hProg[0]);
    while (cur < need) {
        int loops = ((need - cur) >> 5) + 1;   // ~1 sleep-pair per 32 steps
        for (int s = 0; s < loops; ++s) {
            __builtin_amdgcn_s_sleep(32);
            __builtin_amdgcn_s_sleep(32);
        }
        cur = ld_rlx_i(&hProg[0]);
    }
    CFENCE();

    const float* src = (t == 257) ? cfin : (Hs + ((t >= 256 ? 255 : t) * BATCH));
    const float hv = src[qd * 32 + (lane & 31)];

    size_t base = (t < 256) ? ((size_t)t * 16384)
                : (t == 256 ? (size_t)4194304 : (size_t)4210688);
    base += (size_t)qd * 4096;
#pragma unroll 8
    for (int j = 0; j < 64; ++j) {
        const float v = __shfl(hv, j >> 1);
        const f32x4 val = {v, v, v, v};
        __builtin_nontemporal_store(val, (f32x4*)(out4 + base + j * 64 + lane));
    }
}

extern "C" void kernel_launch(void* const* d_in, const int* in_sizes, int n_in,
                              void* d_out, int out_size, void* d_ws, size_t ws_size,
                              hipStream_t stream)
{
    const float* inp = (const float*)d_in[0];
    const float* Wf  = (const float*)d_in[1];
    const float* bfv = (const float*)d_in[2];
    const float* Pf  = (const float*)d_in[3];
    const float* Wi  = (const float*)d_in[4];
    const float* biv = (const float*)d_in[5];
    const float* Pi  = (const float*)d_in[6];
    const float* Wg  = (const float*)d_in[7];
    const float* bgv = (const float*)d_in[8];
    const float* Pg  = (const float*)d_in[9];
    const float* Wo  = (const float*)d_in[10];
    const float* bov = (const float*)d_in[11];
    const float* Po  = (const float*)d_in[12];

    float4* X4   = (float4*)d_ws;                     // NROWS + PF*BATCH
    float*  Hs   = (float*)(X4 + NROWS + PF * BATCH); // 32768
    float*  cfin = Hs + NROWS;                        // 128
    float*  gc   = cfin + BATCH;                      // 40
    int*    hProg = (int*)(gc + 40);                  // 2

    prep<<<1 + GEMV_BLOCKS, 256, 0, stream>>>(inp, Wf, Wi, Wg, Wo,
                                              bfv, biv, bgv, bov,
                                              Pf, Pi, Pg, Po,
                                              gc, hProg, X4);
    scan_write<<<1 + WRITER_BLOCKS, 256, 0, stream>>>(X4, gc, Hs, cfin,
                                                      (float4*)d_out, hProg);
}

// Round 16
// 57.600 us; speedup vs baseline: 1.1083x; 1.1083x over previous
//
#include <hip/hip_runtime.h>
#include <math.h>

#define T_STEPS 256
#define BATCH   128
#define DIMD    512
#define NROWS   (T_STEPS * BATCH)   // 32768
#define PF      16                  // chunk size (LDS staging granularity)
#define NCHUNK  (T_STEPS / PF)      // 16
#define WRITER_BLOCKS 258
#define GEMV_BLOCKS 2048            // 16 rows/block, 4 rows/wave

#define INV2PI  0.15915494309189535f
#define TWO_L2E 2.8853900817779268f

#define AGENT __HIP_MEMORY_SCOPE_AGENT

typedef float f32x4 __attribute__((ext_vector_type(4)));

#if __has_builtin(__builtin_amdgcn_sinf)
#define HW_SIN(x) __builtin_amdgcn_sinf(x)   // sin(2*pi*x), x in revolutions
#else
__device__ __forceinline__ float HW_SIN(float x) { return __sinf(x * 6.283185307179586f); }
#endif
#if __has_builtin(__builtin_amdgcn_exp2f)
#define EXP2(x) __builtin_amdgcn_exp2f(x)
#else
#define EXP2(x) exp2f(x)
#endif
#if __has_builtin(__builtin_amdgcn_rcpf)
#define RCP(x) __builtin_amdgcn_rcpf(x)
#else
#define RCP(x) (1.0f / (x))
#endif

// Horner deg-7
#define P7(s, c7,c6,c5,c4,c3,c2,c1,c0) \
  fmaf(fmaf(fmaf(fmaf(fmaf(fmaf(fmaf((c7),(s),(c6)),(s),(c5)),(s),(c4)),(s),(c3)),(s),(c2)),(s),(c1)),(s),(c0))

// Agent-scope relaxed ops (sc-flagged; no wbl2/inv cache maintenance).
__device__ __forceinline__ void  st_rlx(float* p, float v) {
    __hip_atomic_store(p, v, __ATOMIC_RELAXED, AGENT);
}
__device__ __forceinline__ void  st_rlx_i(int* p, int v) {
    __hip_atomic_store(p, v, __ATOMIC_RELAXED, AGENT);
}
__device__ __forceinline__ int   ld_rlx_i(const int* p) {
    return __hip_atomic_load(p, __ATOMIC_RELAXED, AGENT);
}
#define CFENCE()  asm volatile("" ::: "memory")

// ---------------------------------------------------------------------------
// prep: block 0 = qconsts (4 gates, one wave each); blocks 1.. = gemv.
// qconsts fits, per gate, the deg-7 Chebyshev interpolant of
//   G(s) = act(A + R*s),  s in [-1,1]   (act = sigmoid for f,i,o; tanh for g)
// — valid because |A + R*s| <= |E| <= 1 (Z-expectation of a unit state).
// Fit is ALL-F32 with HW intrinsics (R15's f64 libm fit cost ~10us serial).
// gc layout (floats): [8g..8g+7] monomial coeffs of gate g;
//                     [32+g] = sumWh/2pi; [36+g] = phi_rev.
// X4[t*B+b] = (dot + b0)/2pi  (phase folded by the staging waves).
// ---------------------------------------------------------------------------
__global__ __launch_bounds__(256) void prep(
    const float* __restrict__ inp,
    const float* __restrict__ Wf, const float* __restrict__ Wi,
    const float* __restrict__ Wg, const float* __restrict__ Wo,
    const float* __restrict__ bfp, const float* __restrict__ bip,
    const float* __restrict__ bgp, const float* __restrict__ bop,
    const float* __restrict__ Pf, const float* __restrict__ Pi,
    const float* __restrict__ Pg, const float* __restrict__ Po,
    float* __restrict__ gc, int* __restrict__ hProg,
    float4* __restrict__ X4)
{
    const int bid  = blockIdx.x;
    const int wv   = threadIdx.x >> 6;
    const int lane = threadIdx.x & 63;

    if (bid == 0) {
        // ================= qconsts =================
        if (threadIdx.x == 0) { hProg[0] = 0; hProg[1] = 0; }
        const int g = wv;
        const float* P = (g == 0) ? Pf : (g == 1) ? Pi : (g == 2) ? Pg : Po;
        const float* W = (g == 0) ? Wf : (g == 1) ? Wi : (g == 2) ? Wg : Wo;

        __shared__ float s0r[4][256], s0i[4][256], s1r[4][256], s1i[4][256];

#pragma unroll
        for (int j = 0; j < 4; ++j) {
            const int k = lane + 64 * j;
            s0r[g][k] = (k == 0)   ? 1.0f : 0.0f;  s0i[g][k] = 0.0f;
            s1r[g][k] = (k == 128) ? 1.0f : 0.0f;  s1i[g][k] = 0.0f;
        }
        __syncthreads();

        for (int l = 0; l < 2; ++l) {
            for (int w = 0; w < 8; ++w) {
                const float phi = P[l * 24 + w * 3 + 0];
                const float th  = P[l * 24 + w * 3 + 1];
                const float om  = P[l * 24 + w * 3 + 2];
                float sh, chh; __sincosf(0.5f * th, &sh, &chh);
                float sp, cp;  __sincosf(0.5f * (phi + om), &sp, &cp);
                float sm, cm;  __sincosf(0.5f * (phi - om), &sm, &cm);
                const float m00r =  cp * chh, m00i = -sp * chh;
                const float m01r = -cm * sh,  m01i = -sm * sh;
                const float m10r =  cm * sh,  m10i = -sm * sh;
                const float m11r =  cp * chh, m11i =  sp * chh;

                const int shift = 7 - w;
                const int mask  = 1 << shift;

                float n0r[4], n0i[4], n1r[4], n1i[4];
#pragma unroll
                for (int j = 0; j < 4; ++j) {
                    const int k  = lane + 64 * j;
                    const int bit = (k >> shift) & 1;
                    const int i0 = k & ~mask, i1 = k | mask;
                    const float a0r = s0r[g][i0], a0i = s0i[g][i0];
                    const float a1r = s0r[g][i1], a1i = s0i[g][i1];
                    const float b0r = s1r[g][i0], b0i = s1i[g][i0];
                    const float b1r = s1r[g][i1], b1i = s1i[g][i1];
                    const float mr0 = bit ? m10r : m00r, mi0 = bit ? m10i : m00i;
                    const float mr1 = bit ? m11r : m01r, mi1 = bit ? m11i : m01i;
                    n0r[j] = mr0 * a0r - mi0 * a0i + mr1 * a1r - mi1 * a1i;
                    n0i[j] = mr0 * a0i + mi0 * a0r + mr1 * a1i + mi1 * a1r;
                    n1r[j] = mr0 * b0r - mi0 * b0i + mr1 * b1r - mi1 * b1i;
                    n1i[j] = mr0 * b0i + mi0 * b0r + mr1 * b1i + mi1 * b1r;
                }
                __syncthreads();
#pragma unroll
                for (int j = 0; j < 4; ++j) {
                    const int k = lane + 64 * j;
                    s0r[g][k] = n0r[j]; s0i[g][k] = n0i[j];
                    s1r[g][k] = n1r[j]; s1i[g][k] = n1i[j];
                }
                __syncthreads();
            }
            // CNOT chain permutation
            float n0r[4], n0i[4], n1r[4], n1i[4];
#pragma unroll
            for (int j = 0; j < 4; ++j) {
                int src = lane + 64 * j;
                for (int w = 6; w >= 0; --w) {
                    const int cb = (src >> (7 - w)) & 1;
                    src ^= cb << (6 - w);
                }
                n0r[j] = s0r[g][src]; n0i[j] = s0i[g][src];
                n1r[j] = s1r[g][src]; n1i[j] = s1i[g][src];
            }
            __syncthreads();
#pragma unroll
            for (int j = 0; j < 4; ++j) {
                const int k = lane + 64 * j;
                s0r[g][k] = n0r[j]; s0i[g][k] = n0i[j];
                s1r[g][k] = n1r[j]; s1i[g][k] = n1i[j];
            }
            __syncthreads();
        }

        float t00 = 0, t11 = 0, t01 = 0;
#pragma unroll
        for (int j = 0; j < 4; ++j) {
            const int k = lane + 64 * j;
            const float z = (k < 128) ? 1.0f : -1.0f;
            t00 += z * (s0r[g][k] * s0r[g][k] + s0i[g][k] * s0i[g][k]);
            t11 += z * (s1r[g][k] * s1r[g][k] + s1i[g][k] * s1i[g][k]);
            t01 += z * (s0i[g][k] * s1r[g][k] - s0r[g][k] * s1i[g][k]);
        }
        float tsw = 0;
#pragma unroll
        for (int j = 0; j < 8; ++j) tsw += W[512 + lane + 64 * j];

        for (int off = 32; off; off >>= 1) {
            t00 += __shfl_xor(t00, off);
            t11 += __shfl_xor(t11, off);
            t01 += __shfl_xor(t01, off);
            tsw += __shfl_xor(tsw, off);
        }
        if (lane == 0) {
            const float A  = 0.5f * (t00 + t11);
            const float Bc = 0.5f * (t00 - t11);
            const float Bs = -t01;
            const float R  = sqrtf(Bc * Bc + Bs * Bs);
            const float ph = atan2f(Bc, Bs) * INV2PI;

            // ---- deg-7 Chebyshev interpolation of act(A + R*s), f32 ----
            float xn[8], a[8];
#pragma unroll
            for (int j = 0; j < 8; ++j) {
                xn[j] = __cosf(3.14159265358979f * (2 * j + 1) / 16.0f);
                const float e = A + R * xn[j];
                if (g == 2) {
                    const float t2 = __expf(2.0f * e);
                    a[j] = (t2 - 1.0f) / (t2 + 1.0f);        // tanh(e)
                } else {
                    a[j] = 1.0f / (1.0f + __expf(-e));       // sigmoid(e)
                }
            }
            // Newton divided differences
#pragma unroll
            for (int k = 1; k < 8; ++k)
#pragma unroll
                for (int j = 7; j >= 1; --j)
                    if (j >= k) a[j] = (a[j] - a[j - 1]) / (xn[j] - xn[j - k]);
            // Newton -> monomial
            float m[8] = {0, 0, 0, 0, 0, 0, 0, 0};
            m[0] = a[7];
#pragma unroll
            for (int k = 6; k >= 0; --k) {
#pragma unroll
                for (int i = 7; i >= 1; --i) m[i] = m[i - 1] - xn[k] * m[i];
                m[0] = -xn[k] * m[0] + a[k];
            }
#pragma unroll
            for (int j = 0; j < 8; ++j) gc[8 * g + j] = m[j];
            gc[32 + g] = tsw * INV2PI;
            gc[36 + g] = ph;
        }
        return;
    }

    // ================= gemv: 4 rows per wave =================
    const int rowbase = (bid - 1) * 16 + wv * 4;

    const float4* wfp = (const float4*)Wf;
    const float4* wip = (const float4*)Wi;
    const float4* wgp = (const float4*)Wg;
    const float4* wop = (const float4*)Wo;
    const float4 fa = wfp[lane], fb = wfp[lane + 64];
    const float4 ia = wip[lane], ib = wip[lane + 64];
    const float4 ga = wgp[lane], gb = wgp[lane + 64];
    const float4 oa = wop[lane], ob = wop[lane + 64];

    const float4* xr = (const float4*)(inp + (size_t)rowbase * DIMD);
    float sums[4][4];   // [row][gate]
#pragma unroll
    for (int r = 0; r < 4; ++r) {
        const float4 xa = xr[r * 128 + lane];
        const float4 xb = xr[r * 128 + lane + 64];
        sums[r][0] = xa.x * fa.x + xa.y * fa.y + xa.z * fa.z + xa.w * fa.w
                   + xb.x * fb.x + xb.y * fb.y + xb.z * fb.z + xb.w * fb.w;
        sums[r][1] = xa.x * ia.x + xa.y * ia.y + xa.z * ia.z + xa.w * ia.w
                   + xb.x * ib.x + xb.y * ib.y + xb.z * ib.z + xb.w * ib.w;
        sums[r][2] = xa.x * ga.x + xa.y * ga.y + xa.z * ga.z + xa.w * ga.w
                   + xb.x * gb.x + xb.y * gb.y + xb.z * gb.z + xb.w * gb.w;
        sums[r][3] = xa.x * oa.x + xa.y * oa.y + xa.z * oa.z + xa.w * oa.w
                   + xb.x * ob.x + xb.y * ob.y + xb.z * ob.z + xb.w * ob.w;
    }
#pragma unroll
    for (int r = 0; r < 4; ++r)
#pragma unroll
        for (int g = 0; g < 4; ++g)
            for (int off = 32; off; off >>= 1)
                sums[r][g] += __shfl_xor(sums[r][g], off);

    if (lane == 0) {
        const float b0f = bfp[0], b0i = bip[0], b0g = bgp[0], b0o = bop[0];
#pragma unroll
        for (int r = 0; r < 4; ++r) {
            X4[rowbase + r] = make_float4((sums[r][0] + b0f) * INV2PI,
                                          (sums[r][1] + b0i) * INV2PI,
                                          (sums[r][2] + b0g) * INV2PI,
                                          (sums[r][3] + b0o) * INV2PI);
        }
    }
}

// ---------------------------------------------------------------------------
// Fused scan + broadcast. Grid 259 x 256.
// Block 0: producer/consumer split (R14 structure). Consumers use fitted
// polynomials: per step 4 sin + 28 fma + exp2/rcp tanh tail — 6
// transcendentals instead of 11, chain depth 3 trans instead of 5.
// Blocks 1..258: writers (deficit-proportional sleep, NT output stores).
// ---------------------------------------------------------------------------
__global__ __launch_bounds__(256) void scan_write(
    const float4* __restrict__ X4, const float* __restrict__ gc,
    float* __restrict__ Hs, float* __restrict__ cfin,
    float4* __restrict__ out4, int* __restrict__ hProg)
{
    const int bid  = blockIdx.x;
    const int tid  = threadIdx.x;
    const int wv   = tid >> 6;
    const int lane = tid & 63;

    if (bid == 0) {
        __shared__ float4 xbuf[2][PF][BATCH];   // 64 KB double buffer

        const float phf = gc[36], phi_ = gc[37], phg = gc[38], pho = gc[39];

        if (tid >= BATCH) {
            // -------- producer prologue: stage chunk 0 into buf 0 --------
            const int b = tid - BATCH;
#pragma unroll
            for (int j = 0; j < PF; ++j) {
                const float4 v = X4[j * BATCH + b];
                xbuf[0][j][b] = make_float4(v.x + phf, v.y + phi_,
                                            v.z + phg, v.w + pho);
            }
        }
        __syncthreads();

        // gate polynomial coefficients (named scalars — rule #20)
        const float f0 = gc[0],  f1 = gc[1],  f2 = gc[2],  f3 = gc[3];
        const float f4 = gc[4],  f5 = gc[5],  f6 = gc[6],  f7 = gc[7];
        const float i0 = gc[8],  i1 = gc[9],  i2 = gc[10], i3 = gc[11];
        const float i4 = gc[12], i5 = gc[13], i6 = gc[14], i7 = gc[15];
        const float g0 = gc[16], g1 = gc[17], g2 = gc[18], g3 = gc[19];
        const float g4 = gc[20], g5 = gc[21], g6 = gc[22], g7 = gc[23];
        const float o0 = gc[24], o1 = gc[25], o2 = gc[26], o3 = gc[27];
        const float o4 = gc[28], o5 = gc[29], o6 = gc[30], o7 = gc[31];
        const float swf = gc[32], swi = gc[33], swg = gc[34], swo = gc[35];

        float c = 0.0f, h = 0.0f;
        for (int k = 0; k < NCHUNK; ++k) {
            const int tb = k * PF;
            if (tid >= BATCH) {
                // -------- producer: stage chunk k+1 (pad covers k=15) ----
                const int b  = tid - BATCH;
                const int nb = (k + 1) & 1;
#pragma unroll
                for (int j = 0; j < PF; ++j) {
                    const float4 v = X4[(tb + PF + j) * BATCH + b];
                    xbuf[nb][j][b] = make_float4(v.x + phf, v.y + phi_,
                                                 v.z + phg, v.w + pho);
                }
            } else {
                // -------- consumer: 16 steps from xbuf[k&1] --------------
                const int b  = tid;
                const int cb = k & 1;
                float4 xv = xbuf[cb][0][b];
#pragma unroll
                for (int j = 0; j < PF; ++j) {
                    float4 nx;
                    if (j < PF - 1) nx = xbuf[cb][j + 1][b];  // 2-deep pipe
                    const float thf = fmaf(h, swf, xv.x);
                    const float thi = fmaf(h, swi, xv.y);
                    const float thg = fmaf(h, swg, xv.z);
                    const float tho = fmaf(h, swo, xv.w);
                    const float sf = HW_SIN(thf);
                    const float si = HW_SIN(thi);
                    const float sg = HW_SIN(thg);
                    const float so = HW_SIN(tho);
                    const float fg = P7(sf, f7,f6,f5,f4,f3,f2,f1,f0);
                    const float ig = P7(si, i7,i6,i5,i4,i3,i2,i1,i0);
                    const float gg = P7(sg, g7,g6,g5,g4,g3,g2,g1,g0);
                    const float og = P7(so, o7,o6,o5,o4,o3,o2,o1,o0);
                    c = fmaf(fg, c, ig * gg);
                    const float ec = EXP2(c * TWO_L2E);
                    const float y  = RCP(ec + 1.0f);
                    const float t2 = og * y;
                    h = fmaf(-2.0f, t2, og);                  // o*tanh(c)
                    st_rlx(&Hs[(tb + j) * BATCH + b], h);
                    xv = nx;
                }
                if (k == NCHUNK - 1) st_rlx(&cfin[b], c);
            }
            __syncthreads();   // handoff; each wave drains its own vm ops
            if ((k & 3) == 3 && tid == 0)
                st_rlx_i(&hProg[0], tb + PF);   // t = 64,128,192,256
        }
        return;
    }

    // ---------------- writers ----------------
    const int t  = bid - 1;           // 0..257 (256=hx, 257=cx)
    const int qd = wv;                // quarter: b in [qd*32, qd*32+32)
    const int need = (t < 256) ? ((t >> 6) + 1) << 6 : 256;

    int cur = ld_rlx_i(&hProg[0]);
    while (cur < need) {
        int loops = ((need - cur) >> 5) + 1;   // ~1 sleep-pair per 32 steps
        for (int s = 0; s < loops; ++s) {
            __builtin_amdgcn_s_sleep(32);
            __builtin_amdgcn_s_sleep(32);
        }
        cur = ld_rlx_i(&hProg[0]);
    }
    CFENCE();

    const float* src = (t == 257) ? cfin : (Hs + ((t >= 256 ? 255 : t) * BATCH));
    const float hv = src[qd * 32 + (lane & 31)];

    size_t base = (t < 256) ? ((size_t)t * 16384)
                : (t == 256 ? (size_t)4194304 : (size_t)4210688);
    base += (size_t)qd * 4096;
#pragma unroll 8
    for (int j = 0; j < 64; ++j) {
        const float v = __shfl(hv, j >> 1);
        const f32x4 val = {v, v, v, v};
        __builtin_nontemporal_store(val, (f32x4*)(out4 + base + j * 64 + lane));
    }
}

extern "C" void kernel_launch(void* const* d_in, const int* in_sizes, int n_in,
                              void* d_out, int out_size, void* d_ws, size_t ws_size,
                              hipStream_t stream)
{
    const float* inp = (const float*)d_in[0];
    const float* Wf  = (const float*)d_in[1];
    const float* bfv = (const float*)d_in[2];
    const float* Pf  = (const float*)d_in[3];
    const float* Wi  = (const float*)d_in[4];
    const float* biv = (const float*)d_in[5];
    const float* Pi  = (const float*)d_in[6];
    const float* Wg  = (const float*)d_in[7];
    const float* bgv = (const float*)d_in[8];
    const float* Pg  = (const float*)d_in[9];
    const float* Wo  = (const float*)d_in[10];
    const float* bov = (const float*)d_in[11];
    const float* Po  = (const float*)d_in[12];

    float4* X4   = (float4*)d_ws;                     // NROWS + PF*BATCH
    float*  Hs   = (float*)(X4 + NROWS + PF * BATCH); // 32768
    float*  cfin = Hs + NROWS;                        // 128
    float*  gc   = cfin + BATCH;                      // 40
    int*    hProg = (int*)(gc + 40);                  // 2

    prep<<<1 + GEMV_BLOCKS, 256, 0, stream>>>(inp, Wf, Wi, Wg, Wo,
                                              bfv, biv, bgv, bov,
                                              Pf, Pi, Pg, Po,
                                              gc, hProg, X4);
    scan_write<<<1 + WRITER_BLOCKS, 256, 0, stream>>>(X4, gc, Hs, cfin,
                                                      (float4*)d_out, hProg);
}